// Round 5
// baseline (347.156 us; speedup 1.0000x reference)
//
#include <hip/hip_runtime.h>
#include <math.h>

#define B 1024
#define T 512
#define S 48
#define SOS 47

// broadcast lane n's value of v to all lanes (uniform -> SGPR)
__device__ __forceinline__ float rdlane(float v, int n) {
    return __int_as_float(__builtin_amdgcn_readlane(__float_as_int(v), n));
}

// ---------------------------------------------------------------------------
// Fused CRF loss. One wave per row; lane i owns state i; expT row in VGPRs.
// Scan kept in exp space with DELAYED normalization:
//   invariant  true_score_i = log(q_i) + M   (r_s == exp(-l_s) pending)
//   live step: q' = (expT q) * exp(emis - er) * r_s ;  M += er + l_s
//              then r_s = rcp(d1), l_s = log(d1)   [off critical chain]
//
// KEY (round-5): the q broadcast goes through v_readlane -> SGPR, NOT LDS.
// Rounds 1-4 all did 12x ds_read_b128/step; the DS pipe is per-CU and four
// single-wave blocks share it -> ~576 cyc/step of DS serialization (the
// measured ~860 cyc/step plateau). VALU is per-SIMD: 48 readlane + 48
// v_fmac(SGPR,VGPR) has no cross-wave sharing -> ~240 cyc/step issue-bound.
// No LDS in the scan loop except a 1-byte uniform mask-bitmap read / 8 steps.
// ---------------------------------------------------------------------------
__global__ __launch_bounds__(64)
__attribute__((amdgpu_waves_per_eu(1, 1)))
void crf_fused(const float* __restrict__ feat,
               const int* __restrict__ states,
               const float* __restrict__ mask,
               const float* __restrict__ trans,
               float* __restrict__ out) {
    __shared__ unsigned long long mbits[T / 64];    // 512-bit mask bitmap
    const int b = blockIdx.x;
    const int lane = threadIdx.x;
    const int elane = (lane < S) ? lane : 0;        // lanes 48-63 shadow lane 0
    const float* f_b = feat + (size_t)b * T * S;
    const float* m_b = mask + b * T;
    const int* st_b = states + b * T;

    // ---- numerator + mask-bitmap build (latency overlaps expT setup) ----
    float nsum = 0.f;
#pragma unroll
    for (int k2 = 0; k2 < T / 64; ++k2) {
        const int t = lane + k2 * 64;
        const int st = st_b[t];
        const int pv = (t == 0) ? SOS : st_b[t - 1];
        const float m = m_b[t];
        nsum += (f_b[t * S + st] + trans[st * S + pv]) * m;
        const unsigned long long bal = __ballot(m != 0.f);
        if (lane == 0) mbits[k2] = bal;
    }

    // ---- expT row for this lane; exp(-9999) underflows to exact 0 ----
    float expT[S];
    {
        const float4* t4 = (const float4*)(trans + elane * S);
#pragma unroll
        for (int j4 = 0; j4 < S / 4; ++j4) {
            const float4 tv = t4[j4];
            expT[4 * j4 + 0] = (lane < S) ? __expf(tv.x) : 0.f;
            expT[4 * j4 + 1] = (lane < S) ? __expf(tv.y) : 0.f;
            expT[4 * j4 + 2] = (lane < S) ? __expf(tv.z) : 0.f;
            expT[4 * j4 + 3] = (lane < S) ? __expf(tv.w) : 0.f;
        }
    }

    // ---- scan state ----
    float q = (lane == SOS) ? 1.f : 0.f;      // lanes >= 48 stay 0 forever
    float M = 0.f;
    float r_s = 1.f, l_s = 0.f;               // pending normalizer: r_s == exp(-l_s)

    // emission prefetch, double-buffered 8-step blocks (~2000 cyc of age)
    float ering[2][8];
#pragma unroll
    for (int k = 0; k < 8; ++k)
        ering[0][k] = f_b[k * S + elane];

#pragma unroll 1
    for (int tb = 0; tb < T / 8; ++tb) {
        const int pb = tb & 1;
        // issue next block's emission loads now; consumed a full block later
        const int tn = ((tb + 1) & (T / 8 - 1)) * 8;   // wrap: last refill unused
#pragma unroll
        for (int k = 0; k < 8; ++k)
            ering[pb ^ 1][k] = f_b[(tn + k) * S + elane];
        // this block's 8 mask bits (uniform; volatile so it can't be hoisted)
        const unsigned int mbyte =
            ((const volatile unsigned char*)mbits)[tb];
#pragma unroll
        for (int k = 0; k < 8; ++k) {
            // off-chain: per-lane factor from prefetched emission
            const float emis = ering[pb][k];
            const float er = rdlane(emis, 1);
            const float F = __expf(emis - er) * r_s;
            // broadcast q into scalars (uniform -> SGPR), then VGPRxSGPR dot
            float ax = 0.f, ay = 0.f, az = 0.f, aw = 0.f;
#pragma unroll
            for (int j4 = 0; j4 < S / 4; ++j4) {
                const float q0 = rdlane(q, 4 * j4 + 0);
                const float q1 = rdlane(q, 4 * j4 + 1);
                const float q2 = rdlane(q, 4 * j4 + 2);
                const float q3 = rdlane(q, 4 * j4 + 3);
                ax = fmaf(expT[4 * j4 + 0], q0, ax);
                ay = fmaf(expT[4 * j4 + 1], q1, ay);
                az = fmaf(expT[4 * j4 + 2], q2, az);
                aw = fmaf(expT[4 * j4 + 3], q3, aw);
            }
            const float d = (ax + ay) + (az + aw);
            const float qn = d * F;
            const bool live = ((mbyte >> k) & 1u) != 0u;
            q = live ? qn : q;                  // SELECT, never blend
            // off-chain: next normalizer + shift bookkeeping
            M = live ? (M + er + l_s) : M;      // uses OLD l_s, then update
            const float dr = rdlane(d, 1);      // lane1 dot: provably > 0
            const float nl = __logf(dr);
            const float nr = __builtin_amdgcn_rcpf(dr);
            r_s = live ? nr : r_s;
            l_s = live ? nl : l_s;
        }
    }

    // ---- epilogue: denom = M + log(sum_i q_i); out = denom - numer ----
    float ps = q;                               // lanes >= 48 hold 0
#pragma unroll
    for (int off = 32; off > 0; off >>= 1) {
        ps += __shfl_xor(ps, off, 64);
        nsum += __shfl_xor(nsum, off, 64);
    }
    if (lane == 0) out[b] = M + __logf(ps) - nsum;
}

extern "C" void kernel_launch(void* const* d_in, const int* in_sizes, int n_in,
                              void* d_out, int out_size, void* d_ws, size_t ws_size,
                              hipStream_t stream) {
    const float* feat   = (const float*)d_in[0];   // (B,T,S) f32
    const int*   states = (const int*)d_in[1];     // (B,T) i32
    const float* mask   = (const float*)d_in[2];   // (B,T) f32
    const float* trans  = (const float*)d_in[3];   // (S,S) f32
    float* out = (float*)d_out;                    // (B,) f32

    crf_fused<<<dim3(B), dim3(64), 0, stream>>>(feat, states, mask, trans, out);
}

// Round 6
// 310.329 us; speedup vs baseline: 1.1187x; 1.1187x over previous
//
#include <hip/hip_runtime.h>
#include <math.h>

#define B 1024
#define T 512
#define S 48
#define SOS 47

typedef _Float16 half2v __attribute__((ext_vector_type(2)));
typedef _Float16 half8v __attribute__((ext_vector_type(8)));

// broadcast lane 1's value to all lanes (uniform -> SGPR)
__device__ __forceinline__ float rdlane1(float v) {
    return __int_as_float(__builtin_amdgcn_readlane(__float_as_int(v), 1));
}

// ---------------------------------------------------------------------------
// Fused CRF loss. One wave per row; lane i owns state i.
// Exp-space scan, normalized to state 1 every step:
//   t_i = (sum_j expT[i][j] q_j) * exp(emis_i)     [q in f16, dot2 pairs]
//   q'_i = t_i * rcp(t_1)                          [one readlane on chain]
//   C   += log t_1   == -log(prod r)  -> tracked as product P with exponent
//          stripping (5 int ops, off-chain; no per-step log/er readlane).
// Telescoping: C = s_1(final) - s_1(0) exactly; denom = C + log(sum q).
// q broadcast: 6x ds_read_b128 of f16[48] (was 12 for f32) -- DS pipe is
// per-CU and shared by 4 waves, so halving read count halves the measured
// ~576 cyc/CU/step DS occupancy. Dot: 24x v_dot2_f32_f16 (was 48 fma).
// f16 range: q <= e^10.5 ~ 36k < 65504; spread >= e^-10.5 ~ 3e-5 (denorm ok).
// ---------------------------------------------------------------------------
__global__ __launch_bounds__(64)
__attribute__((amdgpu_waves_per_eu(1, 1)))
void crf_fused(const float* __restrict__ feat,
               const int* __restrict__ states,
               const float* __restrict__ mask,
               const float* __restrict__ trans,
               float* __restrict__ out) {
    __shared__ __align__(16) _Float16 qbuf[2][64];
    __shared__ unsigned long long mbits[T / 64];    // 512-bit mask bitmap
    const int b = blockIdx.x;
    const int lane = threadIdx.x;
    const int elane = (lane < S) ? lane : 0;        // lanes 48-63 shadow lane 0
    const float* f_b = feat + (size_t)b * T * S;
    const float* m_b = mask + b * T;
    const int* st_b = states + b * T;

    // ---- numerator + mask-bitmap build (latency overlaps expT setup) ----
    float nsum = 0.f;
#pragma unroll
    for (int k2 = 0; k2 < T / 64; ++k2) {
        const int t = lane + k2 * 64;
        const int st = st_b[t];
        const int pv = (t == 0) ? SOS : st_b[t - 1];
        const float m = m_b[t];
        nsum += (f_b[t * S + st] + trans[st * S + pv]) * m;
        const unsigned long long bal = __ballot(m != 0.f);
        if (lane == 0) mbits[k2] = bal;
    }

    // ---- expT row for this lane as f16 pairs; exp(-9999) -> exact 0 ----
    half2v eT[S / 2];
    {
        const float4* t4 = (const float4*)(trans + elane * S);
#pragma unroll
        for (int j4 = 0; j4 < S / 4; ++j4) {
            const float4 tv = t4[j4];
            const float e0 = (lane < S) ? __expf(tv.x) : 0.f;
            const float e1 = (lane < S) ? __expf(tv.y) : 0.f;
            const float e2 = (lane < S) ? __expf(tv.z) : 0.f;
            const float e3 = (lane < S) ? __expf(tv.w) : 0.f;
            eT[2 * j4 + 0] = half2v{(_Float16)e0, (_Float16)e1};
            eT[2 * j4 + 1] = half2v{(_Float16)e2, (_Float16)e3};
        }
    }

    // ---- scan state ----
    float q = (lane == SOS) ? 1.f : 0.f;      // lanes >= 48 stay 0 forever
    qbuf[0][lane] = (_Float16)q;
    float P = 1.f;                            // product of applied rcp's
    int cexp = 0;                             // stripped exponent of P

    // emission prefetch, double-buffered 8-step blocks
    float ering[2][8];
#pragma unroll
    for (int k = 0; k < 8; ++k)
        ering[0][k] = f_b[k * S + elane];

#pragma unroll 1
    for (int tb = 0; tb < T / 8; ++tb) {
        const int pbk = tb & 1;
        // issue next block's emission loads now; consumed a full block later
        const int tn = ((tb + 1) & (T / 8 - 1)) * 8;   // wrap: last refill unused
#pragma unroll
        for (int k = 0; k < 8; ++k)
            ering[pbk ^ 1][k] = f_b[(tn + k) * S + elane];
        // this block's 8 mask bits (uniform; volatile so it can't be hoisted)
        const unsigned int mbyte =
            ((const volatile unsigned char*)mbits)[tb];
#pragma unroll
        for (int k = 0; k < 8; ++k) {
            asm volatile("" ::: "memory");    // order prev f16 write vs reads
            // off-chain: per-lane emission factor (no shift, no readlane)
            const float E = __expf(ering[pbk][k]);
            // dot d_i = expT[i] . q  via f16 dot2 on LDS broadcast reads
            const half8v* qb = (const half8v*)&qbuf[k & 1][0];
            float ax = 0.f, ay = 0.f, az = 0.f, aw = 0.f;
#pragma unroll
            for (int c = 0; c < 6; ++c) {
                const half8v h = qb[c];
                const half2v p0 = __builtin_shufflevector(h, h, 0, 1);
                const half2v p1 = __builtin_shufflevector(h, h, 2, 3);
                const half2v p2 = __builtin_shufflevector(h, h, 4, 5);
                const half2v p3 = __builtin_shufflevector(h, h, 6, 7);
                ax = __builtin_amdgcn_fdot2(eT[4 * c + 0], p0, ax, false);
                ay = __builtin_amdgcn_fdot2(eT[4 * c + 1], p1, ay, false);
                az = __builtin_amdgcn_fdot2(eT[4 * c + 2], p2, az, false);
                aw = __builtin_amdgcn_fdot2(eT[4 * c + 3], p3, aw, false);
            }
            const float d = (ax + ay) + (az + aw);
            const float t = d * E;
            const float t1 = rdlane1(t);       // state 1: provably > 0
            const float r = __builtin_amdgcn_rcpf(t1);
            const float qn = t * r;
            const bool live = ((mbyte >> k) & 1u) != 0u;
            q = live ? qn : q;                 // SELECT, never blend
            qbuf[(k + 1) & 1][lane] = (_Float16)q;
            // off-chain: normalizer product with exponent stripping
            const float f = live ? r : 1.f;
            P *= f;
            const int pbits = __float_as_int(P);
            cexp += (pbits >> 23) - 127;
            P = __int_as_float((pbits & 0x007FFFFF) | 0x3F800000);
        }
    }

    // ---- epilogue: C = -log(P*2^cexp); denom = C + log(sum q) ----
    float ps = q;                              // lanes >= 48 hold 0
#pragma unroll
    for (int off = 32; off > 0; off >>= 1) {
        ps += __shfl_xor(ps, off, 64);
        nsum += __shfl_xor(nsum, off, 64);
    }
    if (lane == 0) {
        const float C = -((float)cexp * 0.69314718056f + __logf(P));
        out[b] = C + __logf(ps) - nsum;
    }
}

extern "C" void kernel_launch(void* const* d_in, const int* in_sizes, int n_in,
                              void* d_out, int out_size, void* d_ws, size_t ws_size,
                              hipStream_t stream) {
    const float* feat   = (const float*)d_in[0];   // (B,T,S) f32
    const int*   states = (const int*)d_in[1];     // (B,T) i32
    const float* mask   = (const float*)d_in[2];   // (B,T) f32
    const float* trans  = (const float*)d_in[3];   // (S,S) f32
    float* out = (float*)d_out;                    // (B,) f32

    crf_fused<<<dim3(B), dim3(64), 0, stream>>>(feat, states, mask, trans, out);
}